// Round 11
// baseline (189.254 us; speedup 1.0000x reference)
//
#include <hip/hip_runtime.h>

typedef __attribute__((ext_vector_type(8))) _Float16 f16x8;
typedef __attribute__((ext_vector_type(4))) float f32x4;

#define GLOBAL_AS __attribute__((address_space(1)))
#define LDS_AS __attribute__((address_space(3)))

static constexpr int Bb = 4, LL = 2048, DD = 1024, DI = 2048, DS = 16;
static constexpr int MROWS = Bb * LL;   // 8192
static constexpr int N1 = 2 * DI;       // 4096
static constexpr int K1 = DD;           // 1024 (single-pass fp16)
static constexpr int N2 = DD;           // 1024
static constexpr int K2 = DI;           // 2048

__device__ __forceinline__ unsigned short f2h(float f) {
  _Float16 h = (_Float16)f;
  union { _Float16 h; unsigned short u; } c; c.h = h;
  return c.u;
}
__device__ __forceinline__ float h2f(unsigned short u) {
  union { unsigned short u; _Float16 h; } c; c.u = u;
  return (float)c.h;
}

// ---------------- LayerNorm -> fp16 A1h [8192][1024] ------------------------
__global__ __launch_bounds__(256) void ln_half_kernel(
    const float* __restrict__ x, const float* __restrict__ lnw,
    const float* __restrict__ lnb, unsigned short* __restrict__ A1) {
  const int r = blockIdx.x;
  const int tid = threadIdx.x;
  const float4 v = reinterpret_cast<const float4*>(x + (size_t)r * DD)[tid];
  float s = v.x + v.y + v.z + v.w;
#pragma unroll
  for (int off = 32; off >= 1; off >>= 1) s += __shfl_xor(s, off, 64);
  __shared__ float red[8];
  const int wid = tid >> 6;
  if ((tid & 63) == 0) red[wid] = s;
  __syncthreads();
  const float mu = (red[0] + red[1] + red[2] + red[3]) * (1.0f / DD);
  const float dx = v.x - mu, dy = v.y - mu, dz = v.z - mu, dw = v.w - mu;
  float ss = dx * dx + dy * dy + dz * dz + dw * dw;
#pragma unroll
  for (int off = 32; off >= 1; off >>= 1) ss += __shfl_xor(ss, off, 64);
  if ((tid & 63) == 0) red[4 + wid] = ss;
  __syncthreads();
  const float var = (red[4] + red[5] + red[6] + red[7]) * (1.0f / DD);
  const float rs = rsqrtf(var + 1e-5f);
  const float4 w4 = reinterpret_cast<const float4*>(lnw)[tid];
  const float4 b4 = reinterpret_cast<const float4*>(lnb)[tid];
  ushort4 h4;
  h4.x = f2h(dx * rs * w4.x + b4.x);
  h4.y = f2h(dy * rs * w4.y + b4.y);
  h4.z = f2h(dz * rs * w4.z + b4.z);
  h4.w = f2h(dw * rs * w4.w + b4.w);
  *reinterpret_cast<ushort4*>(&A1[(size_t)r * DD + tid * 4]) = h4;
}

// ------------- generic fp32 -> fp16 converter (n4 float4s) ------------------
__global__ __launch_bounds__(256) void f32_to_f16_kernel(
    const float* __restrict__ W, unsigned short* __restrict__ O) {
  const int gid = blockIdx.x * 256 + threadIdx.x;
  const float4 w = reinterpret_cast<const float4*>(W)[gid];
  ushort4 h4;
  h4.x = f2h(w.x); h4.y = f2h(w.y); h4.z = f2h(w.z); h4.w = f2h(w.w);
  reinterpret_cast<ushort4*>(O)[gid] = h4;
}

// ======== 256x256 tile, BK=32, 4-buffer deep-prefetch GEMM (fp16) ===========
// C[M][N] = A[M][K] * B[N][K]^T, output fp16.
// Round 11 (T4): 4 LDS buffers (4 x 32KB = 128KB), prefetch depth 2.
// Per tile t: stage(t+2) [4 loads] -> s_waitcnt vmcnt(8) (t+1,t+2 stay in
// flight; NEVER drain to 0 in steady state) -> raw s_barrier + sched_barrier
// -> 12 ds_read_b128 + 32 MFMA, compiler-scheduled.
// Swizzle (64B rows): LDS[r*32 + c8*8] holds global[r][(c8^(r&3))*8];
// read offset swzk = ((q ^ (fr&3))<<3).
__global__ __launch_bounds__(512, 2) void gemm_bt_256(
    const unsigned short* __restrict__ A, const unsigned short* __restrict__ B,
    unsigned short* __restrict__ C, int M, int N, int K) {
  __shared__ unsigned short sm[4][2][256 * 32];  // [slot][A/B][tile] = 128 KB
  const int tid = threadIdx.x;
  const int wid = tid >> 6;
  const int lane = tid & 63;
  const int wm = wid >> 2;   // 0..1
  const int wn = wid & 3;    // 0..3
  const int mt = M >> 8;
  const int cpx = gridDim.x >> 3;
  const int bid = blockIdx.x;
  const int sw = (bid & 7) * cpx + (bid >> 3);
  const int bm = sw % mt;
  const int bn = sw / mt;
  const size_t arow0 = (size_t)bm * 256;
  const size_t brow0 = (size_t)bn * 256;

  // staging source pointers (pre-swizzled for 4-chunk rows)
  const unsigned short* gA[2];
  const unsigned short* gB[2];
#pragma unroll
  for (int j = 0; j < 2; ++j) {
    const int idx = j * 512 + tid;          // 0..1023
    const int prow = idx >> 2;              // 0..255
    const int scol = ((idx & 3) ^ (prow & 3)) << 3;
    gA[j] = A + (arow0 + prow) * (size_t)K + scol;
    gB[j] = B + (brow0 + prow) * (size_t)K + scol;
  }
  auto stage = [&](int slot) {
#pragma unroll
    for (int j = 0; j < 2; ++j) {
      __builtin_amdgcn_global_load_lds((const GLOBAL_AS void*)gA[j],
          (LDS_AS void*)&sm[slot][0][(j * 512 + tid) * 8], 16, 0, 0);
      gA[j] += 32;
    }
#pragma unroll
    for (int j = 0; j < 2; ++j) {
      __builtin_amdgcn_global_load_lds((const GLOBAL_AS void*)gB[j],
          (LDS_AS void*)&sm[slot][1][(j * 512 + tid) * 8], 16, 0, 0);
      gB[j] += 32;
    }
  };

  const int q = lane >> 4;
  const int fr = lane & 15;
  const int swzk = ((q ^ (fr & 3)) << 3);   // elems, constant per lane

  int arows[8], brows[4];
#pragma unroll
  for (int mf = 0; mf < 8; ++mf) arows[mf] = ((wm << 7) + mf * 16 + fr) * 32;
#pragma unroll
  for (int nf = 0; nf < 4; ++nf) brows[nf] = ((wn << 6) + nf * 16 + fr) * 32;

  f32x4 acc[8][4] = {};

  const int NTK = K >> 5;  // 32 tiles
  stage(0);
  stage(1);

  for (int t = 0; t < NTK; ++t) {
    const int slot = t & 3;
    if (t + 2 < NTK) stage((t + 2) & 3);
    // counted drain: only tile t's 4 loads must be complete
    if (t + 2 < NTK)      asm volatile("s_waitcnt vmcnt(8)" ::: "memory");
    else if (t + 1 < NTK) asm volatile("s_waitcnt vmcnt(4)" ::: "memory");
    else                  asm volatile("s_waitcnt vmcnt(0)" ::: "memory");
    __builtin_amdgcn_s_barrier();
    __builtin_amdgcn_sched_barrier(0);
    f16x8 af[8], bf[4];
#pragma unroll
    for (int mf = 0; mf < 8; ++mf)
      af[mf] = *reinterpret_cast<const f16x8*>(&sm[slot][0][arows[mf] + swzk]);
#pragma unroll
    for (int nf = 0; nf < 4; ++nf)
      bf[nf] = *reinterpret_cast<const f16x8*>(&sm[slot][1][brows[nf] + swzk]);
#pragma unroll
    for (int mf = 0; mf < 8; ++mf)
#pragma unroll
      for (int nf = 0; nf < 4; ++nf)
        acc[mf][nf] = __builtin_amdgcn_mfma_f32_16x16x32_f16(
            af[mf], bf[nf], acc[mf][nf], 0, 0, 0);
  }

  // all ds_reads of the last tile are consumed by MFMAs (compiler lgkmcnt);
  // no trailing barrier needed before the epilogue (per-thread data only).
  const int fcol = lane & 15;
  const int frow4 = (lane >> 4) << 2;
#pragma unroll
  for (int mf = 0; mf < 8; ++mf)
#pragma unroll
    for (int nf = 0; nf < 4; ++nf) {
      const size_t row0 = arow0 + (wm << 7) + mf * 16 + frow4;
      const size_t col = brow0 + (wn << 6) + nf * 16 + fcol;
#pragma unroll
      for (int j = 0; j < 4; ++j)
        C[(row0 + j) * (size_t)N + col] = f2h(acc[mf][nf][j]);
    }
}

// ===== 256x128 tile, BK=64, 8-wave, swizzled un-pinned GEMM (fp16 -> fp32) ==
__global__ __launch_bounds__(512, 2) void gemm_bt_256n128(
    const unsigned short* __restrict__ A, const unsigned short* __restrict__ B,
    float* __restrict__ C, int M, int N, int K) {
  __shared__ unsigned short sm[2][24576];  // [buf][A 16384 | B 8192] = 96 KB
  const int tid = threadIdx.x;
  const int wid = tid >> 6;
  const int lane = tid & 63;
  const int wm = wid >> 2;   // 0..1  (128 rows each)
  const int wn = wid & 3;    // 0..3  (32 cols each)
  const int mt = M >> 8;
  const int cpx = gridDim.x >> 3;
  const int bid = blockIdx.x;
  const int sw = (bid & 7) * cpx + (bid >> 3);
  const int bm = sw % mt;
  const int bn = sw / mt;
  const size_t arow0 = (size_t)bm * 256;
  const size_t brow0 = (size_t)bn * 128;

  const unsigned short* gA[4];
  const unsigned short* gB[2];
#pragma unroll
  for (int j = 0; j < 4; ++j) {
    const int idx = j * 512 + tid;
    const int prow = idx >> 3;
    const int scol = ((idx & 7) ^ (prow & 7)) << 3;
    gA[j] = A + (arow0 + prow) * (size_t)K + scol;
  }
#pragma unroll
  for (int j = 0; j < 2; ++j) {
    const int idx = j * 512 + tid;
    const int prow = idx >> 3;          // < 128
    const int scol = ((idx & 7) ^ (prow & 7)) << 3;
    gB[j] = B + (brow0 + prow) * (size_t)K + scol;
  }
  auto stageA = [&](int buf) {
#pragma unroll
    for (int j = 0; j < 4; ++j) {
      __builtin_amdgcn_global_load_lds((const GLOBAL_AS void*)gA[j],
          (LDS_AS void*)&sm[buf][(j * 512 + (wid << 6)) * 8], 16, 0, 0);
      gA[j] += 64;
    }
  };
  auto stageB = [&](int buf) {
#pragma unroll
    for (int j = 0; j < 2; ++j) {
      __builtin_amdgcn_global_load_lds((const GLOBAL_AS void*)gB[j],
          (LDS_AS void*)&sm[buf][16384 + (j * 512 + (wid << 6)) * 8], 16, 0, 0);
      gB[j] += 64;
    }
  };

  const int q = lane >> 4;
  const int l7 = lane & 7;
  const int fr = lane & 15;
  int swz[2];
  swz[0] = (q << 3) ^ (l7 << 3);
  swz[1] = (32 + (q << 3)) ^ (l7 << 3);

  int arows[8], brows[2];
#pragma unroll
  for (int mf = 0; mf < 8; ++mf) arows[mf] = ((wm << 7) + mf * 16 + fr) * 64;
#pragma unroll
  for (int nf = 0; nf < 2; ++nf) brows[nf] = 16384 + ((wn << 5) + nf * 16 + fr) * 64;

  f32x4 acc[8][2] = {};

  const int NTK = K >> 6;
  stageA(0);
  stageB(0);
  __syncthreads();

  for (int t = 0; t < NTK; ++t) {
    const int cur = t & 1, nxt = cur ^ 1;
    if (t + 1 < NTK) { stageA(nxt); stageB(nxt); }
    f16x8 af[8][2], bf[2][2];
#pragma unroll
    for (int mf = 0; mf < 8; ++mf)
#pragma unroll
      for (int ks = 0; ks < 2; ++ks)
        af[mf][ks] = *reinterpret_cast<const f16x8*>(&sm[cur][arows[mf] + swz[ks]]);
#pragma unroll
    for (int nf = 0; nf < 2; ++nf)
#pragma unroll
      for (int ks = 0; ks < 2; ++ks)
        bf[nf][ks] = *reinterpret_cast<const f16x8*>(&sm[cur][brows[nf] + swz[ks]]);
#pragma unroll
    for (int ks = 0; ks < 2; ++ks)
#pragma unroll
      for (int mf = 0; mf < 8; ++mf)
#pragma unroll
        for (int nf = 0; nf < 2; ++nf)
          acc[mf][nf] = __builtin_amdgcn_mfma_f32_16x16x32_f16(
              af[mf][ks], bf[nf][ks], acc[mf][nf], 0, 0, 0);
    __syncthreads();
  }

  const int fcol = lane & 15;
  const int frow4 = (lane >> 4) << 2;
#pragma unroll
  for (int mf = 0; mf < 8; ++mf)
#pragma unroll
    for (int nf = 0; nf < 2; ++nf) {
      const size_t row0 = arow0 + (wm << 7) + mf * 16 + frow4;
      const size_t col = brow0 + (wn << 5) + nf * 16 + fcol;
#pragma unroll
      for (int j = 0; j < 4; ++j)
        C[(row0 + j) * (size_t)N + col] = acc[mf][nf][j];
    }
}

// ------------- scalar-filter bidirectional scan + SiLU gate ------------------
__global__ __launch_bounds__(256) void scan_kernel(
    const unsigned short* __restrict__ xp, const float* __restrict__ Bm,
    const float* __restrict__ Cm, unsigned short* __restrict__ oss) {
  constexpr int T = 32, KH = 8;
  const int blk = blockIdx.x;
  const int igrp = blk & 7;
  const int c = (blk >> 3) & 63;
  const int b = blk >> 9;
  const int tid = threadIdx.x;
  const int i = igrp * 256 + tid;
  float d = 0.f;
  {
    const float4* bp = reinterpret_cast<const float4*>(Bm + (size_t)i * DS);
    const float4* cp = reinterpret_cast<const float4*>(Cm + (size_t)i * DS);
#pragma unroll
    for (int qv = 0; qv < 4; ++qv) {
      const float4 bv = bp[qv], cv = cp[qv];
      d += bv.x * cv.x + bv.y * cv.y + bv.z * cv.z + bv.w * cv.w;
    }
  }
  const float dh = 0.5f * d;
  const int t0 = c * T;
  const size_t rowbase = (size_t)b * LL;
  float yf[T];
  float g = 0.f;
  {
    const int hstart = (t0 >= KH) ? t0 - KH : 0;
    for (int t = hstart; t < t0; ++t)
      g = fmaf(0.01f, g, h2f(xp[(rowbase + t) * (size_t)N1 + i]));
#pragma unroll
    for (int j = 0; j < T; ++j) {
      g = fmaf(0.01f, g, h2f(xp[(rowbase + t0 + j) * (size_t)N1 + i]));
      yf[j] = g;
    }
  }
  g = 0.f;
  {
    const int tend = (t0 + T - 1 + KH <= LL - 1) ? (t0 + T - 1 + KH) : (LL - 1);
    for (int t = tend; t >= t0 + T; --t)
      g = fmaf(0.01f, g, h2f(xp[(rowbase + t) * (size_t)N1 + i]));
#pragma unroll
    for (int j = T - 1; j >= 0; --j) {
      const size_t row = rowbase + t0 + j;
      g = fmaf(0.01f, g, h2f(xp[row * (size_t)N1 + i]));
      const float gt = h2f(xp[row * (size_t)N1 + DI + i]);
      const float sg = gt / (1.f + expf(-gt));
      const float o = (yf[j] + g) * dh * sg;
      oss[row * (size_t)DI + i] = f2h(o);
    }
  }
}

extern "C" void kernel_launch(void* const* d_in, const int* in_sizes, int n_in,
                              void* d_out, int out_size, void* d_ws, size_t ws_size,
                              hipStream_t stream) {
  (void)in_sizes; (void)n_in; (void)out_size; (void)ws_size;
  const float* x          = (const float*)d_in[0];
  const float* in_proj_w  = (const float*)d_in[1];
  const float* B_mat      = (const float*)d_in[3];
  const float* C_mat      = (const float*)d_in[4];
  const float* out_proj_w = (const float*)d_in[5];
  const float* ln_w       = (const float*)d_in[6];
  const float* ln_b       = (const float*)d_in[7];
  float* out = (float*)d_out;

  char* ws = (char*)d_ws;
  unsigned short* A1  = (unsigned short*)ws; ws += (size_t)MROWS * K1 * 2;  // 16.8 MB
  unsigned short* B1  = (unsigned short*)ws; ws += (size_t)N1 * K1 * 2;    //  8.4 MB
  unsigned short* B2  = (unsigned short*)ws; ws += (size_t)N2 * K2 * 2;    //  4.2 MB
  unsigned short* OSS = (unsigned short*)ws; ws += (size_t)MROWS * DI * 2; // 33.6 MB
  unsigned short* XP  = (unsigned short*)ws; ws += (size_t)MROWS * N1 * 2; // 67.1 MB

  f32_to_f16_kernel<<<dim3((N1 * K1 / 4) / 256), dim3(256), 0, stream>>>(in_proj_w, B1);
  f32_to_f16_kernel<<<dim3((N2 * K2 / 4) / 256), dim3(256), 0, stream>>>(out_proj_w, B2);
  ln_half_kernel<<<dim3(MROWS), dim3(256), 0, stream>>>(x, ln_w, ln_b, A1);
  gemm_bt_256<<<dim3((MROWS / 256) * (N1 / 256)), dim3(512), 0, stream>>>(A1, B1, XP, MROWS, N1, K1);
  scan_kernel<<<dim3(2048), dim3(256), 0, stream>>>(XP, B_mat, C_mat, OSS);
  gemm_bt_256n128<<<dim3((MROWS / 256) * (N2 / 128)), dim3(512), 0, stream>>>(OSS, B2, out, MROWS, N2, K2);
}

// Round 12
// 187.835 us; speedup vs baseline: 1.0076x; 1.0076x over previous
//
#include <hip/hip_runtime.h>

typedef __attribute__((ext_vector_type(8))) _Float16 f16x8;
typedef __attribute__((ext_vector_type(4))) float f32x4;

#define GLOBAL_AS __attribute__((address_space(1)))
#define LDS_AS __attribute__((address_space(3)))

static constexpr int Bb = 4, LL = 2048, DD = 1024, DI = 2048, DS = 16;
static constexpr int MROWS = Bb * LL;   // 8192
static constexpr int N1 = 2 * DI;       // 4096
static constexpr int K1 = DD;           // 1024 (single-pass fp16)
static constexpr int N2 = DD;           // 1024
static constexpr int K2 = DI;           // 2048

__device__ __forceinline__ unsigned short f2h(float f) {
  _Float16 h = (_Float16)f;
  union { _Float16 h; unsigned short u; } c; c.h = h;
  return c.u;
}
__device__ __forceinline__ float h2f(unsigned short u) {
  union { unsigned short u; _Float16 h; } c; c.u = u;
  return (float)c.h;
}

// ---------------- LayerNorm -> fp16 A1h [8192][1024] ------------------------
__global__ __launch_bounds__(256) void ln_half_kernel(
    const float* __restrict__ x, const float* __restrict__ lnw,
    const float* __restrict__ lnb, unsigned short* __restrict__ A1) {
  const int r = blockIdx.x;
  const int tid = threadIdx.x;
  const float4 v = reinterpret_cast<const float4*>(x + (size_t)r * DD)[tid];
  float s = v.x + v.y + v.z + v.w;
#pragma unroll
  for (int off = 32; off >= 1; off >>= 1) s += __shfl_xor(s, off, 64);
  __shared__ float red[8];
  const int wid = tid >> 6;
  if ((tid & 63) == 0) red[wid] = s;
  __syncthreads();
  const float mu = (red[0] + red[1] + red[2] + red[3]) * (1.0f / DD);
  const float dx = v.x - mu, dy = v.y - mu, dz = v.z - mu, dw = v.w - mu;
  float ss = dx * dx + dy * dy + dz * dz + dw * dw;
#pragma unroll
  for (int off = 32; off >= 1; off >>= 1) ss += __shfl_xor(ss, off, 64);
  if ((tid & 63) == 0) red[4 + wid] = ss;
  __syncthreads();
  const float var = (red[4] + red[5] + red[6] + red[7]) * (1.0f / DD);
  const float rs = rsqrtf(var + 1e-5f);
  const float4 w4 = reinterpret_cast<const float4*>(lnw)[tid];
  const float4 b4 = reinterpret_cast<const float4*>(lnb)[tid];
  ushort4 h4;
  h4.x = f2h(dx * rs * w4.x + b4.x);
  h4.y = f2h(dy * rs * w4.y + b4.y);
  h4.z = f2h(dz * rs * w4.z + b4.z);
  h4.w = f2h(dw * rs * w4.w + b4.w);
  *reinterpret_cast<ushort4*>(&A1[(size_t)r * DD + tid * 4]) = h4;
}

// ------------- generic fp32 -> fp16 converter (n4 float4s) ------------------
__global__ __launch_bounds__(256) void f32_to_f16_kernel(
    const float* __restrict__ W, unsigned short* __restrict__ O) {
  const int gid = blockIdx.x * 256 + threadIdx.x;
  const float4 w = reinterpret_cast<const float4*>(W)[gid];
  ushort4 h4;
  h4.x = f2h(w.x); h4.y = f2h(w.y); h4.z = f2h(w.z); h4.w = f2h(w.w);
  reinterpret_cast<ushort4*>(O)[gid] = h4;
}

// ======== 256x256 tile, BK=32, 4-buffer deep-prefetch GEMM (fp16) ===========
// C[M][N] = A[M][K] * B[N][K]^T, output fp16.
// T4: 4 LDS slots (128KB), prefetch depth 2, counted vmcnt (8/4/0 ladder),
// raw s_barrier + sched_barrier(0), compiler-scheduled ds_read/MFMA.
// Swizzle (64B rows, round-12 fix): chunk c8 of row r lives at LDS chunk
// c8 ^ ((r>>1)&3). Bank slot = (r&1)*16 + (q^((r>>1)&3))*4 -> every 8
// consecutive lanes hit all 8 slots exactly once (conflict-free).
__global__ __launch_bounds__(512, 2) void gemm_bt_256(
    const unsigned short* __restrict__ A, const unsigned short* __restrict__ B,
    unsigned short* __restrict__ C, int M, int N, int K) {
  __shared__ unsigned short sm[4][2][256 * 32];  // [slot][A/B][tile] = 128 KB
  const int tid = threadIdx.x;
  const int wid = tid >> 6;
  const int lane = tid & 63;
  const int wm = wid >> 2;   // 0..1
  const int wn = wid & 3;    // 0..3
  const int mt = M >> 8;
  const int cpx = gridDim.x >> 3;
  const int bid = blockIdx.x;
  const int sw = (bid & 7) * cpx + (bid >> 3);
  const int bm = sw % mt;
  const int bn = sw / mt;
  const size_t arow0 = (size_t)bm * 256;
  const size_t brow0 = (size_t)bn * 256;

  // staging source pointers (pre-swizzled: chunk idx&3 <- global chunk
  // (idx&3) ^ ((prow>>1)&3))
  const unsigned short* gA[2];
  const unsigned short* gB[2];
#pragma unroll
  for (int j = 0; j < 2; ++j) {
    const int idx = j * 512 + tid;          // 0..1023
    const int prow = idx >> 2;              // 0..255
    const int scol = ((idx & 3) ^ ((prow >> 1) & 3)) << 3;
    gA[j] = A + (arow0 + prow) * (size_t)K + scol;
    gB[j] = B + (brow0 + prow) * (size_t)K + scol;
  }
  auto stage = [&](int slot) {
#pragma unroll
    for (int j = 0; j < 2; ++j) {
      __builtin_amdgcn_global_load_lds((const GLOBAL_AS void*)gA[j],
          (LDS_AS void*)&sm[slot][0][(j * 512 + tid) * 8], 16, 0, 0);
      gA[j] += 32;
    }
#pragma unroll
    for (int j = 0; j < 2; ++j) {
      __builtin_amdgcn_global_load_lds((const GLOBAL_AS void*)gB[j],
          (LDS_AS void*)&sm[slot][1][(j * 512 + tid) * 8], 16, 0, 0);
      gB[j] += 32;
    }
  };

  const int q = lane >> 4;
  const int fr = lane & 15;
  const int swzk = ((q ^ ((fr >> 1) & 3)) << 3);  // elems, constant per lane

  int arows[8], brows[4];
#pragma unroll
  for (int mf = 0; mf < 8; ++mf) arows[mf] = ((wm << 7) + mf * 16 + fr) * 32;
#pragma unroll
  for (int nf = 0; nf < 4; ++nf) brows[nf] = ((wn << 6) + nf * 16 + fr) * 32;

  f32x4 acc[8][4] = {};

  const int NTK = K >> 5;  // 32 tiles
  stage(0);
  stage(1);

  for (int t = 0; t < NTK; ++t) {
    const int slot = t & 3;
    if (t + 2 < NTK) stage((t + 2) & 3);
    // counted drain: only tile t's 4 loads must be complete
    if (t + 2 < NTK)      asm volatile("s_waitcnt vmcnt(8)" ::: "memory");
    else if (t + 1 < NTK) asm volatile("s_waitcnt vmcnt(4)" ::: "memory");
    else                  asm volatile("s_waitcnt vmcnt(0)" ::: "memory");
    __builtin_amdgcn_s_barrier();
    __builtin_amdgcn_sched_barrier(0);
    f16x8 af[8], bf[4];
#pragma unroll
    for (int mf = 0; mf < 8; ++mf)
      af[mf] = *reinterpret_cast<const f16x8*>(&sm[slot][0][arows[mf] + swzk]);
#pragma unroll
    for (int nf = 0; nf < 4; ++nf)
      bf[nf] = *reinterpret_cast<const f16x8*>(&sm[slot][1][brows[nf] + swzk]);
#pragma unroll
    for (int mf = 0; mf < 8; ++mf)
#pragma unroll
      for (int nf = 0; nf < 4; ++nf)
        acc[mf][nf] = __builtin_amdgcn_mfma_f32_16x16x32_f16(
            af[mf], bf[nf], acc[mf][nf], 0, 0, 0);
  }

  const int fcol = lane & 15;
  const int frow4 = (lane >> 4) << 2;
#pragma unroll
  for (int mf = 0; mf < 8; ++mf)
#pragma unroll
    for (int nf = 0; nf < 4; ++nf) {
      const size_t row0 = arow0 + (wm << 7) + mf * 16 + frow4;
      const size_t col = brow0 + (wn << 6) + nf * 16 + fcol;
#pragma unroll
      for (int j = 0; j < 4; ++j)
        C[(row0 + j) * (size_t)N + col] = f2h(acc[mf][nf][j]);
    }
}

// ===== 256x128 tile, BK=64, 8-wave, swizzled un-pinned GEMM (fp16 -> fp32) ==
__global__ __launch_bounds__(512, 2) void gemm_bt_256n128(
    const unsigned short* __restrict__ A, const unsigned short* __restrict__ B,
    float* __restrict__ C, int M, int N, int K) {
  __shared__ unsigned short sm[2][24576];  // [buf][A 16384 | B 8192] = 96 KB
  const int tid = threadIdx.x;
  const int wid = tid >> 6;
  const int lane = tid & 63;
  const int wm = wid >> 2;   // 0..1  (128 rows each)
  const int wn = wid & 3;    // 0..3  (32 cols each)
  const int mt = M >> 8;
  const int cpx = gridDim.x >> 3;
  const int bid = blockIdx.x;
  const int sw = (bid & 7) * cpx + (bid >> 3);
  const int bm = sw % mt;
  const int bn = sw / mt;
  const size_t arow0 = (size_t)bm * 256;
  const size_t brow0 = (size_t)bn * 128;

  const unsigned short* gA[4];
  const unsigned short* gB[2];
#pragma unroll
  for (int j = 0; j < 4; ++j) {
    const int idx = j * 512 + tid;
    const int prow = idx >> 3;
    const int scol = ((idx & 7) ^ (prow & 7)) << 3;
    gA[j] = A + (arow0 + prow) * (size_t)K + scol;
  }
#pragma unroll
  for (int j = 0; j < 2; ++j) {
    const int idx = j * 512 + tid;
    const int prow = idx >> 3;          // < 128
    const int scol = ((idx & 7) ^ (prow & 7)) << 3;
    gB[j] = B + (brow0 + prow) * (size_t)K + scol;
  }
  auto stageA = [&](int buf) {
#pragma unroll
    for (int j = 0; j < 4; ++j) {
      __builtin_amdgcn_global_load_lds((const GLOBAL_AS void*)gA[j],
          (LDS_AS void*)&sm[buf][(j * 512 + (wid << 6)) * 8], 16, 0, 0);
      gA[j] += 64;
    }
  };
  auto stageB = [&](int buf) {
#pragma unroll
    for (int j = 0; j < 2; ++j) {
      __builtin_amdgcn_global_load_lds((const GLOBAL_AS void*)gB[j],
          (LDS_AS void*)&sm[buf][16384 + (j * 512 + (wid << 6)) * 8], 16, 0, 0);
      gB[j] += 64;
    }
  };

  const int q = lane >> 4;
  const int l7 = lane & 7;
  const int fr = lane & 15;
  int swz[2];
  swz[0] = (q << 3) ^ (l7 << 3);
  swz[1] = (32 + (q << 3)) ^ (l7 << 3);

  int arows[8], brows[2];
#pragma unroll
  for (int mf = 0; mf < 8; ++mf) arows[mf] = ((wm << 7) + mf * 16 + fr) * 64;
#pragma unroll
  for (int nf = 0; nf < 2; ++nf) brows[nf] = 16384 + ((wn << 5) + nf * 16 + fr) * 64;

  f32x4 acc[8][2] = {};

  const int NTK = K >> 6;
  stageA(0);
  stageB(0);
  __syncthreads();

  for (int t = 0; t < NTK; ++t) {
    const int cur = t & 1, nxt = cur ^ 1;
    if (t + 1 < NTK) { stageA(nxt); stageB(nxt); }
    f16x8 af[8][2], bf[2][2];
#pragma unroll
    for (int mf = 0; mf < 8; ++mf)
#pragma unroll
      for (int ks = 0; ks < 2; ++ks)
        af[mf][ks] = *reinterpret_cast<const f16x8*>(&sm[cur][arows[mf] + swz[ks]]);
#pragma unroll
    for (int nf = 0; nf < 2; ++nf)
#pragma unroll
      for (int ks = 0; ks < 2; ++ks)
        bf[nf][ks] = *reinterpret_cast<const f16x8*>(&sm[cur][brows[nf] + swz[ks]]);
#pragma unroll
    for (int ks = 0; ks < 2; ++ks)
#pragma unroll
      for (int mf = 0; mf < 8; ++mf)
#pragma unroll
        for (int nf = 0; nf < 2; ++nf)
          acc[mf][nf] = __builtin_amdgcn_mfma_f32_16x16x32_f16(
              af[mf][ks], bf[nf][ks], acc[mf][nf], 0, 0, 0);
    __syncthreads();
  }

  const int fcol = lane & 15;
  const int frow4 = (lane >> 4) << 2;
#pragma unroll
  for (int mf = 0; mf < 8; ++mf)
#pragma unroll
    for (int nf = 0; nf < 2; ++nf) {
      const size_t row0 = arow0 + (wm << 7) + mf * 16 + frow4;
      const size_t col = brow0 + (wn << 5) + nf * 16 + fcol;
#pragma unroll
      for (int j = 0; j < 4; ++j)
        C[(row0 + j) * (size_t)N + col] = acc[mf][nf][j];
    }
}

// ------------- scalar-filter bidirectional scan + SiLU gate ------------------
__global__ __launch_bounds__(256) void scan_kernel(
    const unsigned short* __restrict__ xp, const float* __restrict__ Bm,
    const float* __restrict__ Cm, unsigned short* __restrict__ oss) {
  constexpr int T = 32, KH = 8;
  const int blk = blockIdx.x;
  const int igrp = blk & 7;
  const int c = (blk >> 3) & 63;
  const int b = blk >> 9;
  const int tid = threadIdx.x;
  const int i = igrp * 256 + tid;
  float d = 0.f;
  {
    const float4* bp = reinterpret_cast<const float4*>(Bm + (size_t)i * DS);
    const float4* cp = reinterpret_cast<const float4*>(Cm + (size_t)i * DS);
#pragma unroll
    for (int qv = 0; qv < 4; ++qv) {
      const float4 bv = bp[qv], cv = cp[qv];
      d += bv.x * cv.x + bv.y * cv.y + bv.z * cv.z + bv.w * cv.w;
    }
  }
  const float dh = 0.5f * d;
  const int t0 = c * T;
  const size_t rowbase = (size_t)b * LL;
  float yf[T];
  float g = 0.f;
  {
    const int hstart = (t0 >= KH) ? t0 - KH : 0;
    for (int t = hstart; t < t0; ++t)
      g = fmaf(0.01f, g, h2f(xp[(rowbase + t) * (size_t)N1 + i]));
#pragma unroll
    for (int j = 0; j < T; ++j) {
      g = fmaf(0.01f, g, h2f(xp[(rowbase + t0 + j) * (size_t)N1 + i]));
      yf[j] = g;
    }
  }
  g = 0.f;
  {
    const int tend = (t0 + T - 1 + KH <= LL - 1) ? (t0 + T - 1 + KH) : (LL - 1);
    for (int t = tend; t >= t0 + T; --t)
      g = fmaf(0.01f, g, h2f(xp[(rowbase + t) * (size_t)N1 + i]));
#pragma unroll
    for (int j = T - 1; j >= 0; --j) {
      const size_t row = rowbase + t0 + j;
      g = fmaf(0.01f, g, h2f(xp[row * (size_t)N1 + i]));
      const float gt = h2f(xp[row * (size_t)N1 + DI + i]);
      const float sg = gt / (1.f + expf(-gt));
      const float o = (yf[j] + g) * dh * sg;
      oss[row * (size_t)DI + i] = f2h(o);
    }
  }
}

extern "C" void kernel_launch(void* const* d_in, const int* in_sizes, int n_in,
                              void* d_out, int out_size, void* d_ws, size_t ws_size,
                              hipStream_t stream) {
  (void)in_sizes; (void)n_in; (void)out_size; (void)ws_size;
  const float* x          = (const float*)d_in[0];
  const float* in_proj_w  = (const float*)d_in[1];
  const float* B_mat      = (const float*)d_in[3];
  const float* C_mat      = (const float*)d_in[4];
  const float* out_proj_w = (const float*)d_in[5];
  const float* ln_w       = (const float*)d_in[6];
  const float* ln_b       = (const float*)d_in[7];
  float* out = (float*)d_out;

  char* ws = (char*)d_ws;
  unsigned short* A1  = (unsigned short*)ws; ws += (size_t)MROWS * K1 * 2;  // 16.8 MB
  unsigned short* B1  = (unsigned short*)ws; ws += (size_t)N1 * K1 * 2;    //  8.4 MB
  unsigned short* B2  = (unsigned short*)ws; ws += (size_t)N2 * K2 * 2;    //  4.2 MB
  unsigned short* OSS = (unsigned short*)ws; ws += (size_t)MROWS * DI * 2; // 33.6 MB
  unsigned short* XP  = (unsigned short*)ws; ws += (size_t)MROWS * N1 * 2; // 67.1 MB

  f32_to_f16_kernel<<<dim3((N1 * K1 / 4) / 256), dim3(256), 0, stream>>>(in_proj_w, B1);
  f32_to_f16_kernel<<<dim3((N2 * K2 / 4) / 256), dim3(256), 0, stream>>>(out_proj_w, B2);
  ln_half_kernel<<<dim3(MROWS), dim3(256), 0, stream>>>(x, ln_w, ln_b, A1);
  gemm_bt_256<<<dim3((MROWS / 256) * (N1 / 256)), dim3(512), 0, stream>>>(A1, B1, XP, MROWS, N1, K1);
  scan_kernel<<<dim3(2048), dim3(256), 0, stream>>>(XP, B_mat, C_mat, OSS);
  gemm_bt_256n128<<<dim3((MROWS / 256) * (N2 / 128)), dim3(512), 0, stream>>>(OSS, B2, out, MROWS, N2, K2);
}